// Round 1
// baseline (5567.236 us; speedup 1.0000x reference)
//
#include <hip/hip_runtime.h>
#include <hip/hip_bf16.h>

// LSTM: L=512 steps, N=64 batch, I=H=1024.
// Round 6: BATCH-GROUP PIPELINED recurrence. Key fact: the recurrence is
// independent per batch (h_{t+1}[b] depends only on h_t[b]); batch-group
// bg = nt = wave already owned its gates. Each step is now 4 slots, one per
// batch-group: {poll 32 flags(bg) | load 8 h-frags(bg) | 16 MFMA | LDS
// partial | barrier | wave==bg: gates+store+flag | x-refill(bg,t+1)}.
// The fabric round-trip for group bg (store->flag->poll->load) now hides
// under the other 3 groups' streaming/MFMA instead of serializing the whole
// step. Same math, same traffic, same flags/ring protocol (flags were
// already per-(WG,wave)=per-(WG,bg)).
//  K1: convert x fp32->bf16 packed + h0 packed to slot 0 + flag init.
//  K2: persistent recurrence, 128 WGs x 256 thr: register-resident weights,
//      per-(wave,bg) producer-subset flag polling, zero fences.
//  K3: y = h @ W_out^T + b_out.
// Packed slab layout [64 x 1024]: elem(row,col) -> byte (col>>3)*1024 + row*16 + (col&7)*2

#define L_STEPS 512
#define NB 64
#define HID 1024
#define GRID_LSTM 128

typedef __bf16 bf16x8 __attribute__((ext_vector_type(8)));
typedef __bf16 bf16x4 __attribute__((ext_vector_type(4)));
typedef __bf16 bf16x2 __attribute__((ext_vector_type(2)));
typedef float  f32x4  __attribute__((ext_vector_type(4)));
typedef float  f32x2  __attribute__((ext_vector_type(2)));
typedef unsigned u32x4 __attribute__((ext_vector_type(4)));

__device__ __forceinline__ float sigmoid_f(float x) {
    return 1.f / (1.f + __expf(-x));
}
__device__ __forceinline__ float tanh_f(float x) {
    return 1.f - 2.f / (1.f + __expf(2.f * x));
}

__global__ void convert_kernel(const float* __restrict__ x, const float* __restrict__ h0,
                               __bf16* __restrict__ xbf, __bf16* __restrict__ hbf,
                               unsigned* __restrict__ bar) {
    unsigned u = blockIdx.x * 256u + threadIdx.x;
    if (u < 512u) bar[u] = 0u;
    const int row = u & 63;
    const int cg  = (u >> 6) & 127;
    if (u < 8192u) {   // h0 -> packed slot 0
        const float* s = h0 + (size_t)row * HID + cg * 8;
        f32x4 a = *(const f32x4*)s, b = *(const f32x4*)(s + 4);
        bf16x8 o;
        o[0]=(__bf16)a[0]; o[1]=(__bf16)a[1]; o[2]=(__bf16)a[2]; o[3]=(__bf16)a[3];
        o[4]=(__bf16)b[0]; o[5]=(__bf16)b[1]; o[6]=(__bf16)b[2]; o[7]=(__bf16)b[3];
        ((bf16x8*)hbf)[u] = o;
    }
    const int t = u >> 13;
    const float* s = x + ((size_t)t * NB + row) * HID + cg * 8;
    f32x4 a = *(const f32x4*)s, b = *(const f32x4*)(s + 4);
    bf16x8 o;
    o[0]=(__bf16)a[0]; o[1]=(__bf16)a[1]; o[2]=(__bf16)a[2]; o[3]=(__bf16)a[3];
    o[4]=(__bf16)b[0]; o[5]=(__bf16)b[1]; o[6]=(__bf16)b[2]; o[7]=(__bf16)b[3];
    ((bf16x8*)xbf)[u] = o;
}

// x half for ONE batch-group on a packed slab; act already includes bg*128.
__device__ __forceinline__ void mfma_x_bg(const __bf16* __restrict__ act,
                                          const bf16x8 (&wfr)[2][8],
                                          f32x4 (&a)[2]) {
    #pragma unroll
    for (int kk = 0; kk < 8; ++kk) {
        bf16x8 b = *(const bf16x8*)(act + kk * 2048);
        #pragma unroll
        for (int mt = 0; mt < 2; ++mt)
            a[mt] = __builtin_amdgcn_mfma_f32_16x16x32_bf16(wfr[mt][kk], b, a[mt], 0, 0, 0);
    }
}

template <bool RING>
__global__ __launch_bounds__(256, 1) void lstm_kernel(
    const float* __restrict__ c0,
    const float* __restrict__ W_ih, const float* __restrict__ W_hh,
    const float* __restrict__ b_ih, const float* __restrict__ b_hh,
    const __bf16* __restrict__ xbf,      // [512] packed 64x1024 slabs
    __bf16* hbuf,                        // RING: [513] slots, else [2] parity
    unsigned* bar,                       // [512] per-(wg,bg) step flags (wg*4+bg)
    float* __restrict__ out)             // d_out: y[65536], h[65536], c[65536]
{
    const int tid  = threadIdx.x;
    const int lane = tid & 63;
    const int w    = tid >> 6;           // wave id: combined-K quarter AND gate batch-group
    const int quad = lane >> 4;
    const int l15  = lane & 15;
    const int hbase = blockIdx.x * 8;

    __shared__ float red[4][64][44];     // [wave][batch][row pad 32->44] = 45056 B

    // ---- weight preload (once, from row-major fp32 W).
    bf16x8 wfx[2][8], wfh[2][8];
    #pragma unroll
    for (int mt = 0; mt < 2; ++mt) {
        const int n    = mt * 16 + l15;
        const int grow = (n >> 3) * HID + hbase + (n & 7);
        #pragma unroll
        for (int kk = 0; kk < 8; ++kk) {
            const int kcol = w * 256 + kk * 32 + quad * 8;
            {
                const float* src = W_ih + (size_t)grow * 1024 + kcol;
                f32x4 a = *(const f32x4*)src;
                f32x4 b = *(const f32x4*)(src + 4);
                bf16x8 f;
                f[0]=(__bf16)a[0]; f[1]=(__bf16)a[1]; f[2]=(__bf16)a[2]; f[3]=(__bf16)a[3];
                f[4]=(__bf16)b[0]; f[5]=(__bf16)b[1]; f[6]=(__bf16)b[2]; f[7]=(__bf16)b[3];
                wfx[mt][kk] = f;
            }
            {
                const float* src = W_hh + (size_t)grow * 1024 + kcol;
                f32x4 a = *(const f32x4*)src;
                f32x4 b = *(const f32x4*)(src + 4);
                bf16x8 f;
                f[0]=(__bf16)a[0]; f[1]=(__bf16)a[1]; f[2]=(__bf16)a[2]; f[3]=(__bf16)a[3];
                f[4]=(__bf16)b[0]; f[5]=(__bf16)b[1]; f[6]=(__bf16)b[2]; f[7]=(__bf16)b[3];
                wfh[mt][kk] = f;
            }
        }
    }

    // per-thread cell state: pairs (cb, cu) and (cb, cu+1).
    // cb = tid>>2 in [16w, 16w+16): wave w owns batch-group w's gates.
    const int p0 = tid * 2;
    const int cb = p0 >> 3;
    const int cu = p0 & 7;
    float c0v = c0[cb * HID + hbase + cu];
    float c1v = c0[cb * HID + hbase + cu + 1];

    float bias0[4], bias1[4];
    #pragma unroll
    for (int gate = 0; gate < 4; ++gate) {
        int gr = gate * HID + hbase + cu;
        bias0[gate] = b_ih[gr] + b_hh[gr];
        bias1[gate] = b_ih[gr + 1] + b_hh[gr + 1];
    }

    // per-lane packed-slab offset (elements); bg adds bg*128
    const int lane_off = (32 * w + quad) * 512 + l15 * 8;
    // packed h store offset (elements): cg = blockIdx, row = cb, col&7 = cu
    const int hstore_off = blockIdx.x * 512 + cb * 8 + cu;

    // poll base: wave w's K-quarter producers are WGs [32w, 32w+32); flag
    // index (32w + j)*4 + bg. 32 flags duplicated across lane halves.
    const int pfl = (32 * w + (lane & 31)) * 4;

    // per-bg accumulators (x partials held across the step, h added per slot)
    f32x4 acc[4][2];
    #pragma unroll
    for (int bg = 0; bg < 4; ++bg) {
        #pragma unroll
        for (int mt = 0; mt < 2; ++mt) { f32x4 z = {0.f,0.f,0.f,0.f}; acc[bg][mt] = z; }
        mfma_x_bg(xbf + lane_off + bg * 128, wfx, acc[bg]);
    }

    for (int t = 0; t < L_STEPS; ++t) {
        const __bf16* hb_slot = hbuf + (size_t)(RING ? t : (t & 1)) * (NB * HID) + lane_off;
        #pragma unroll
        for (int bg = 0; bg < 4; ++bg) {
            // ---- poll this batch-group's 32 producer flags (relaxed, no fences)
            for (;;) {
                unsigned f = __hip_atomic_load(&bar[pfl + bg], __ATOMIC_RELAXED,
                                               __HIP_MEMORY_SCOPE_AGENT);
                if (__all(f >= (unsigned)t)) break;
                __builtin_amdgcn_s_sleep(1);
            }

            // ---- h loads for this group: 8 x 16B per lane (fully coalesced,
            // identical per-instruction pattern to round 5's nt-fixed loads)
            u32x4 hb[8];
            #pragma unroll
            for (int kk = 0; kk < 8; ++kk) {
                const __bf16* p = hb_slot + bg * 128 + kk * 2048;
                if constexpr (RING)
                    asm volatile("global_load_dwordx4 %0, %1, off"
                                 : "=v"(hb[kk]) : "v"(p));
                else
                    asm volatile("global_load_dwordx4 %0, %1, off sc1"
                                 : "=v"(hb[kk]) : "v"(p));
            }
            asm volatile("s_waitcnt vmcnt(4)"
                : "+v"(hb[0]), "+v"(hb[1]), "+v"(hb[2]), "+v"(hb[3]));
            #pragma unroll
            for (int kk = 0; kk < 4; ++kk)
                #pragma unroll
                for (int mt = 0; mt < 2; ++mt)
                    acc[bg][mt] = __builtin_amdgcn_mfma_f32_16x16x32_bf16(
                        wfh[mt][kk], __builtin_bit_cast(bf16x8, hb[kk]),
                        acc[bg][mt], 0, 0, 0);
            asm volatile("s_waitcnt vmcnt(0)"
                : "+v"(hb[4]), "+v"(hb[5]), "+v"(hb[6]), "+v"(hb[7]));
            #pragma unroll
            for (int kk = 4; kk < 8; ++kk)
                #pragma unroll
                for (int mt = 0; mt < 2; ++mt)
                    acc[bg][mt] = __builtin_amdgcn_mfma_f32_16x16x32_bf16(
                        wfh[mt][kk], __builtin_bit_cast(bf16x8, hb[kk]),
                        acc[bg][mt], 0, 0, 0);

            // ---- partials -> LDS (cols bg*16..bg*16+16 only; disjoint per
            // slot, WAR across steps ordered by the per-slot flag protocol)
            #pragma unroll
            for (int mt = 0; mt < 2; ++mt)
                *(f32x4*)&red[w][bg * 16 + l15][mt * 16 + quad * 4] = acc[bg][mt];
            __syncthreads();

            // ---- gate phase: wave bg alone finishes its batch-group while
            // the other waves stream the next group
            if (w == bg) {
                float z0[4], z1[4];
                #pragma unroll
                for (int gate = 0; gate < 4; ++gate) {
                    const int row = gate * 8 + cu;
                    f32x2 s0 = *(const f32x2*)&red[0][cb][row];
                    f32x2 s1 = *(const f32x2*)&red[1][cb][row];
                    f32x2 s2 = *(const f32x2*)&red[2][cb][row];
                    f32x2 s3 = *(const f32x2*)&red[3][cb][row];
                    z0[gate] = s0[0] + s1[0] + s2[0] + s3[0] + bias0[gate];
                    z1[gate] = s0[1] + s1[1] + s2[1] + s3[1] + bias1[gate];
                }
                float ig = sigmoid_f(z0[0]), fg = sigmoid_f(z0[1]);
                float gg = tanh_f(z0[2]),    og = sigmoid_f(z0[3]);
                c0v = fg * c0v + ig * gg;
                float h0v = og * tanh_f(c0v);
                ig = sigmoid_f(z1[0]); fg = sigmoid_f(z1[1]);
                gg = tanh_f(z1[2]);    og = sigmoid_f(z1[3]);
                c1v = fg * c1v + ig * gg;
                float h1v = og * tanh_f(c1v);

                // publish h_{t+1}[bg]: sc1 store (write-through); drain is
                // deferred under the x-refill below, then flag posts.
                bf16x2 hv; hv[0] = (__bf16)h0v; hv[1] = (__bf16)h1v;
                unsigned hbits = __builtin_bit_cast(unsigned, hv);
                const __bf16* dst = hbuf
                    + (size_t)(RING ? (t + 1) : ((t + 1) & 1)) * (NB * HID) + hstore_off;
                asm volatile("global_store_dword %0, %1, off sc1"
                             :: "v"(dst), "v"(hbits) : "memory");
                if (t == L_STEPS - 1) {
                    const int idx = cb * HID + hbase + cu;
                    out[65536 + idx]      = h0v;
                    out[65536 + idx + 1]  = h1v;
                    out[131072 + idx]     = c0v;
                    out[131072 + idx + 1] = c1v;
                }
            }

            // ---- x refill for (t+1, bg): hides the store drain / fills the
            // pipe while other groups' fabric round-trips are in flight
            if (t < L_STEPS - 1) {
                #pragma unroll
                for (int mt = 0; mt < 2; ++mt) { f32x4 z = {0.f,0.f,0.f,0.f}; acc[bg][mt] = z; }
                mfma_x_bg(xbf + (size_t)(t + 1) * (NB * HID) + lane_off + bg * 128,
                          wfx, acc[bg]);
                if (w == bg) {
                    // x loads + compiler waits already drained the sc1 store;
                    // explicit drain is ~free, then post this group's flag.
                    asm volatile("s_waitcnt vmcnt(0)" ::: "memory");
                    if (lane == 0)
                        __hip_atomic_store(&bar[blockIdx.x * 4 + bg], (unsigned)(t + 1),
                                           __ATOMIC_RELAXED, __HIP_MEMORY_SCOPE_AGENT);
                }
            }
        }
    }
}

__global__ void out_kernel(const float* __restrict__ base, const float* __restrict__ Wout,
                           const float* __restrict__ bout, float* __restrict__ y)
{
    const int wv   = (int)((blockIdx.x * 256u + threadIdx.x) >> 6);
    const int lane = threadIdx.x & 63;
    const int b = wv >> 10;
    const int i = wv & 1023;
    const f32x4* hp = (const f32x4*)(base + 65536 + b * HID);
    const f32x4* wp = (const f32x4*)(Wout + (size_t)i * HID);
    float acc = 0.f;
    #pragma unroll
    for (int q = 0; q < 4; ++q) {
        f32x4 hv = hp[q * 64 + lane];
        f32x4 wvv = wp[q * 64 + lane];
        acc += hv[0]*wvv[0] + hv[1]*wvv[1] + hv[2]*wvv[2] + hv[3]*wvv[3];
    }
    #pragma unroll
    for (int off = 32; off > 0; off >>= 1) acc += __shfl_down(acc, off);
    if (lane == 0) y[b * HID + i] = acc + bout[i];
}

extern "C" void kernel_launch(void* const* d_in, const int* in_sizes, int n_in,
                              void* d_out, int out_size, void* d_ws, size_t ws_size,
                              hipStream_t stream)
{
    const float* x    = (const float*)d_in[0];
    const float* h0   = (const float*)d_in[1];
    const float* c0   = (const float*)d_in[2];
    const float* W_ih = (const float*)d_in[3];
    const float* W_hh = (const float*)d_in[4];
    const float* b_ih = (const float*)d_in[5];
    const float* b_hh = (const float*)d_in[6];
    const float* Wout = (const float*)d_in[7];
    const float* bout = (const float*)d_in[8];
    float* out = (float*)d_out;

    // ws layout: xbf (64 MB) | hbuf (ring: 513 slots = 64.1 MB, else 256 KB) | bar
    const size_t XBF_B  = 67108864;                  // 512 x 131072
    const size_t RING_B = 513ull * 131072;           // 67,239,936
    const size_t need_ring = XBF_B + RING_B + 2048;
    const bool ring = ws_size >= need_ring;

    char* ws = (char*)d_ws;
    __bf16* xbf   = (__bf16*)(ws);
    __bf16* hbuf  = (__bf16*)(ws + XBF_B);
    unsigned* bar = (unsigned*)(ws + XBF_B + (ring ? RING_B : 262144));

    convert_kernel<<<16384, 256, 0, stream>>>(x, h0, xbf, hbuf, bar);
    if (ring)
        lstm_kernel<true><<<GRID_LSTM, 256, 0, stream>>>(c0, W_ih, W_hh, b_ih, b_hh,
                                                         xbf, hbuf, bar, out);
    else
        lstm_kernel<false><<<GRID_LSTM, 256, 0, stream>>>(c0, W_ih, W_hh, b_ih, b_hh,
                                                          xbf, hbuf, bar, out);
    out_kernel<<<16384, 256, 0, stream>>>(out, Wout, bout, out);
}

// Round 2
// 2926.155 us; speedup vs baseline: 1.9026x; 1.9026x over previous
//
#include <hip/hip_runtime.h>
#include <hip/hip_bf16.h>

// LSTM: L=512 steps, N=64 batch, I=H=1024.
// Round 7: (a) x-half fully PRECOMPUTED (zx = x@W_ih^T + b for all t) by a
// parallel kernel -- removes 64 MFMA + 128KB x-stream per WG-step from the
// serial recurrence; (b) recurrence re-mapped so each WAVE owns a complete
// 16x16 z-tile = all 4 gates x 4 cols x 16 batches: C-layout puts the 4 gate
// values of one (col,batch) in one lane's 4 acc regs -> gates are lane-local,
// NO LDS, NO __syncthreads, no cross-wave coupling. 8 waves/WG, each with its
// own poll/load/mfma/gate/store/flag chain (round-5's proven ring+flag
// protocol, per-wave granularity). Ring slots 1..511 alias the dead xbf slabs
// (kernel-boundary cache invalidation makes this safe).
// Fallback: verbatim round-5 kernel if ws_size can't fit zx (512MB fp32).

#define L_STEPS 512
#define NB 64
#define HID 1024

typedef __bf16 bf16x8 __attribute__((ext_vector_type(8)));
typedef __bf16 bf16x2 __attribute__((ext_vector_type(2)));
typedef float  f32x4  __attribute__((ext_vector_type(4)));
typedef float  f32x2  __attribute__((ext_vector_type(2)));
typedef unsigned u32x4 __attribute__((ext_vector_type(4)));

__device__ __forceinline__ float sigmoid_f(float x) {
    return 1.f / (1.f + __expf(-x));
}
__device__ __forceinline__ float tanh_f(float x) {
    return 1.f - 2.f / (1.f + __expf(2.f * x));
}

// Packed slab layout [64 x 1024]: elem(row,col) -> idx (col>>3)*512 + row*8 + (col&7)
__global__ void convert_kernel(const float* __restrict__ x, const float* __restrict__ h0,
                               __bf16* __restrict__ xbf, __bf16* __restrict__ hbf,
                               unsigned* __restrict__ bar) {
    unsigned u = blockIdx.x * 256u + threadIdx.x;
    if (u < 1024u) bar[u] = 0u;
    const int row = u & 63;
    const int cg  = (u >> 6) & 127;
    if (u < 8192u) {   // h0 -> packed slot 0
        const float* s = h0 + (size_t)row * HID + cg * 8;
        f32x4 a = *(const f32x4*)s, b = *(const f32x4*)(s + 4);
        bf16x8 o;
        o[0]=(__bf16)a[0]; o[1]=(__bf16)a[1]; o[2]=(__bf16)a[2]; o[3]=(__bf16)a[3];
        o[4]=(__bf16)b[0]; o[5]=(__bf16)b[1]; o[6]=(__bf16)b[2]; o[7]=(__bf16)b[3];
        ((bf16x8*)hbf)[u] = o;
    }
    const int t = u >> 13;
    const float* s = x + ((size_t)t * NB + row) * HID + cg * 8;
    f32x4 a = *(const f32x4*)s, b = *(const f32x4*)(s + 4);
    bf16x8 o;
    o[0]=(__bf16)a[0]; o[1]=(__bf16)a[1]; o[2]=(__bf16)a[2]; o[3]=(__bf16)a[3];
    o[4]=(__bf16)b[0]; o[5]=(__bf16)b[1]; o[6]=(__bf16)b[2]; o[7]=(__bf16)b[3];
    ((bf16x8*)xbf)[u] = o;
}

// ============================ NEW PATH =====================================
// zx precompute: 256 WGs = 64 col-groups(16 cols) x 4 t-quarters.
// Per WG: register-resident W_ih slice (wfx[4][8], rows = gate mt x 16 cols),
// K-split across 4 waves, LDS reduce, write zx[t][col][batch][4 gates] fp32
// with bias folded in. Same MFMA association as round-5's x path.
__global__ __launch_bounds__(256, 1) void zx_kernel(
    const __bf16* __restrict__ xbf, const float* __restrict__ W_ih,
    const float* __restrict__ b_ih, const float* __restrict__ b_hh,
    float* __restrict__ zx)
{
    const int tid = threadIdx.x, lane = tid & 63, w = tid >> 6;
    const int quad = lane >> 4, l15 = lane & 15;
    const int cg = blockIdx.x >> 2, tq = blockIdx.x & 3;
    const int hb16 = cg * 16;

    __shared__ float red[4][64][66];

    // A rows n = mt*16 + l15 -> (gate = mt, col = hb16 + l15)
    bf16x8 wfx[4][8];
    #pragma unroll
    for (int mt = 0; mt < 4; ++mt) {
        const int grow = mt * HID + hb16 + l15;
        #pragma unroll
        for (int kk = 0; kk < 8; ++kk) {
            const float* src = W_ih + (size_t)grow * HID + w * 256 + kk * 32 + quad * 8;
            f32x4 a = *(const f32x4*)src, b = *(const f32x4*)(src + 4);
            bf16x8 f;
            f[0]=(__bf16)a[0]; f[1]=(__bf16)a[1]; f[2]=(__bf16)a[2]; f[3]=(__bf16)a[3];
            f[4]=(__bf16)b[0]; f[5]=(__bf16)b[1]; f[6]=(__bf16)b[2]; f[7]=(__bf16)b[3];
            wfx[mt][kk] = f;
        }
    }

    const int co = tid >> 4;          // [0,16) gather col within group
    const int b0 = (tid & 15) * 4;    // gather batch base
    float bias[4];
    #pragma unroll
    for (int g = 0; g < 4; ++g)
        bias[g] = b_ih[g * HID + hb16 + co] + b_hh[g * HID + hb16 + co];

    const int lane_off = (32 * w + quad) * 512 + l15 * 8;

    for (int t = tq * 128; t < tq * 128 + 128; ++t) {
        const __bf16* act = xbf + (size_t)t * 65536 + lane_off;
        f32x4 acc[4][4];
        #pragma unroll
        for (int mt = 0; mt < 4; ++mt)
            #pragma unroll
            for (int nt = 0; nt < 4; ++nt) { f32x4 z = {0.f,0.f,0.f,0.f}; acc[mt][nt] = z; }
        #pragma unroll
        for (int kk = 0; kk < 8; ++kk) {
            bf16x8 bfr[4];
            #pragma unroll
            for (int nt = 0; nt < 4; ++nt)
                bfr[nt] = *(const bf16x8*)(act + kk * 2048 + nt * 128);
            #pragma unroll
            for (int mt = 0; mt < 4; ++mt)
                #pragma unroll
                for (int nt = 0; nt < 4; ++nt)
                    acc[mt][nt] = __builtin_amdgcn_mfma_f32_16x16x32_bf16(
                        wfx[mt][kk], bfr[nt], acc[mt][nt], 0, 0, 0);
        }
        __syncthreads();      // WAR vs previous gather
        #pragma unroll
        for (int mt = 0; mt < 4; ++mt)
            #pragma unroll
            for (int nt = 0; nt < 4; ++nt)
                *(f32x4*)&red[w][nt * 16 + l15][mt * 16 + quad * 4] = acc[mt][nt];
        __syncthreads();
        float* zrow = zx + (((size_t)t * HID + hb16 + co) * 64 + b0) * 4;
        #pragma unroll
        for (int j = 0; j < 4; ++j) {
            const int b = b0 + j;
            f32x4 zv;
            #pragma unroll
            for (int g = 0; g < 4; ++g)
                zv[g] = bias[g] + red[0][b][g*16+co] + red[1][b][g*16+co]
                                + red[2][b][g*16+co] + red[3][b][g*16+co];
            *(f32x4*)(zrow + j * 4) = zv;
        }
    }
}

// Recurrence: 128 WGs x 512 threads (8 waves = 2 col-halves x 4 batch-quarters).
// Wave (mt,nh): full K=1024, 16 z-rows (4 gates x 4 cols), 16 batches.
// A rows n -> (gate = n&3, col = hbase + mt*4 + (n>>2)); C reg r = gate r of
// (col = hbase+mt*4+quad, batch = nh*16+l15). Gates fully lane-local.
__global__ __launch_bounds__(512, 1) void lstm_wave(
    const float* __restrict__ c0_p,
    const float* __restrict__ W_hh,
    __bf16* xbf,                      // ring: slot t (t>=1) aliases xbf slab t
    const __bf16* __restrict__ h0s,   // slot 0 (packed h0)
    const float* __restrict__ zx,     // [512][1024][64][4] fp32, bias included
    unsigned* bar,                    // [1024]: idx = nh*256 + mt*128 + wg
    float* __restrict__ out)          // d_out: y[65536], h[65536], c[65536]
{
    const int tid  = threadIdx.x;
    const int lane = tid & 63;
    const int w8   = tid >> 6;
    const int nh   = w8 & 3;          // batch quarter
    const int mt   = w8 >> 2;         // col half
    const int quad = lane >> 4;
    const int l15  = lane & 15;
    const int wg   = blockIdx.x;
    const int hbase = wg * 8;

    const int col   = hbase + mt * 4 + quad;
    const int batch = nh * 16 + l15;

    // ---- W_hh fragment preload (32 x bf16x8 = 128 VGPR)
    bf16x8 wfh[32];
    {
        const int wrow = (l15 & 3) * HID + hbase + mt * 4 + (l15 >> 2);
        const float* wr = W_hh + (size_t)wrow * HID + quad * 8;
        #pragma unroll
        for (int kk = 0; kk < 32; ++kk) {
            const float* src = wr + kk * 32;
            f32x4 a = *(const f32x4*)src, b = *(const f32x4*)(src + 4);
            bf16x8 f;
            f[0]=(__bf16)a[0]; f[1]=(__bf16)a[1]; f[2]=(__bf16)a[2]; f[3]=(__bf16)a[3];
            f[4]=(__bf16)b[0]; f[5]=(__bf16)b[1]; f[6]=(__bf16)b[2]; f[7]=(__bf16)b[3];
            wfh[kk] = f;
        }
    }

    float cv = c0_p[batch * HID + col];

    const int bOff  = quad * 512 + nh * 128 + l15 * 8;        // B-frag lane offset
    const int hsOff = wg * 512 + batch * 8 + (mt * 4 + quad); // h-store lane offset
    const size_t zOff = ((size_t)col * 64 + batch) * 4;       // zx lane offset (floats)
    const int fpost = nh * 256 + mt * 128 + wg;
    const int pbase = nh * 256 + lane;                        // poll: 256 flags of nh-block

    u32x4 zxr = *(const u32x4*)(zx + zOff);   // t=0 (compiler load + wait)

    for (int t = 0; t < L_STEPS; ++t) {
        // ---- poll all 256 producer waves of this batch-quarter (relaxed)
        for (;;) {
            unsigned f0 = __hip_atomic_load(&bar[pbase],       __ATOMIC_RELAXED, __HIP_MEMORY_SCOPE_AGENT);
            unsigned f1 = __hip_atomic_load(&bar[pbase + 64],  __ATOMIC_RELAXED, __HIP_MEMORY_SCOPE_AGENT);
            unsigned f2 = __hip_atomic_load(&bar[pbase + 128], __ATOMIC_RELAXED, __HIP_MEMORY_SCOPE_AGENT);
            unsigned f3 = __hip_atomic_load(&bar[pbase + 192], __ATOMIC_RELAXED, __HIP_MEMORY_SCOPE_AGENT);
            if (__all((f0 >= (unsigned)t) && (f1 >= (unsigned)t) &&
                      (f2 >= (unsigned)t) && (f3 >= (unsigned)t))) break;
            __builtin_amdgcn_s_sleep(1);
        }
        // poll's own waitcnt drained all prior vm ops (incl zxr prefetch).

        f32x4 acc_a = __builtin_bit_cast(f32x4, zxr);   // zx includes bias
        f32x4 acc_b = {0.f, 0.f, 0.f, 0.f};

        const __bf16* bp = ((t == 0) ? h0s : (const __bf16*)(xbf + (size_t)t * 65536)) + bOff;

        // ---- 32 h B-frags, rolling window 16 (plain loads: ring slots cold)
        u32x4 hb[16];
        #pragma unroll
        for (int k = 0; k < 16; ++k)
            asm volatile("global_load_dwordx4 %0, %1, off" : "=v"(hb[k]) : "v"(bp + k * 2048));

        asm volatile("s_waitcnt vmcnt(8)"
            : "+v"(hb[0]), "+v"(hb[1]), "+v"(hb[2]), "+v"(hb[3]),
              "+v"(hb[4]), "+v"(hb[5]), "+v"(hb[6]), "+v"(hb[7]));
        #pragma unroll
        for (int k = 0; k < 8; ++k) {
            if (k & 1) acc_b = __builtin_amdgcn_mfma_f32_16x16x32_bf16(
                wfh[k], __builtin_bit_cast(bf16x8, hb[k]), acc_b, 0, 0, 0);
            else       acc_a = __builtin_amdgcn_mfma_f32_16x16x32_bf16(
                wfh[k], __builtin_bit_cast(bf16x8, hb[k]), acc_a, 0, 0, 0);
        }
        #pragma unroll
        for (int k = 0; k < 8; ++k)
            asm volatile("global_load_dwordx4 %0, %1, off" : "=v"(hb[k]) : "v"(bp + (16 + k) * 2048));

        asm volatile("s_waitcnt vmcnt(8)"
            : "+v"(hb[8]), "+v"(hb[9]), "+v"(hb[10]), "+v"(hb[11]),
              "+v"(hb[12]), "+v"(hb[13]), "+v"(hb[14]), "+v"(hb[15]));
        #pragma unroll
        for (int k = 8; k < 16; ++k) {
            if (k & 1) acc_b = __builtin_amdgcn_mfma_f32_16x16x32_bf16(
                wfh[k], __builtin_bit_cast(bf16x8, hb[k]), acc_b, 0, 0, 0);
            else       acc_a = __builtin_amdgcn_mfma_f32_16x16x32_bf16(
                wfh[k], __builtin_bit_cast(bf16x8, hb[k]), acc_a, 0, 0, 0);
        }
        #pragma unroll
        for (int k = 0; k < 8; ++k)
            asm volatile("global_load_dwordx4 %0, %1, off" : "=v"(hb[8 + k]) : "v"(bp + (24 + k) * 2048));

        asm volatile("s_waitcnt vmcnt(8)"
            : "+v"(hb[0]), "+v"(hb[1]), "+v"(hb[2]), "+v"(hb[3]),
              "+v"(hb[4]), "+v"(hb[5]), "+v"(hb[6]), "+v"(hb[7]));
        #pragma unroll
        for (int k = 16; k < 24; ++k) {
            if (k & 1) acc_b = __builtin_amdgcn_mfma_f32_16x16x32_bf16(
                wfh[k], __builtin_bit_cast(bf16x8, hb[k - 16]), acc_b, 0, 0, 0);
            else       acc_a = __builtin_amdgcn_mfma_f32_16x16x32_bf16(
                wfh[k], __builtin_bit_cast(bf16x8, hb[k - 16]), acc_a, 0, 0, 0);
        }
        asm volatile("s_waitcnt vmcnt(0)"
            : "+v"(hb[8]), "+v"(hb[9]), "+v"(hb[10]), "+v"(hb[11]),
              "+v"(hb[12]), "+v"(hb[13]), "+v"(hb[14]), "+v"(hb[15]));
        #pragma unroll
        for (int k = 24; k < 32; ++k) {
            if (k & 1) acc_b = __builtin_amdgcn_mfma_f32_16x16x32_bf16(
                wfh[k], __builtin_bit_cast(bf16x8, hb[k - 16]), acc_b, 0, 0, 0);
            else       acc_a = __builtin_amdgcn_mfma_f32_16x16x32_bf16(
                wfh[k], __builtin_bit_cast(bf16x8, hb[k - 16]), acc_a, 0, 0, 0);
        }

        // ---- gates: fully lane-local (reg r = gate r for this (col,batch))
        f32x4 z = acc_a + acc_b;
        float ig = sigmoid_f(z[0]), fg = sigmoid_f(z[1]);
        float gg = tanh_f(z[2]),    og = sigmoid_f(z[3]);
        cv = fg * cv + ig * gg;
        float hv = og * tanh_f(cv);

        if (t < L_STEPS - 1) {
            // publish h_{t+1}: 2B sc1 store; zx prefetch rides behind it so
            // vmcnt(1) drains the store (oldest) without waiting the prefetch.
            __bf16 hbf16 = (__bf16)hv;
            unsigned hbits = (unsigned)__builtin_bit_cast(unsigned short, hbf16);
            const __bf16* dst = xbf + (size_t)(t + 1) * 65536 + hsOff;
            asm volatile("global_store_short %0, %1, off sc1"
                         :: "v"(dst), "v"(hbits) : "memory");
            const float* zp = zx + ((size_t)(t + 1) << 18) + zOff;
            asm volatile("global_load_dwordx4 %0, %1, off" : "=v"(zxr) : "v"(zp));
            asm volatile("s_waitcnt vmcnt(1)" ::: "memory");
            if (lane == 0)
                __hip_atomic_store(&bar[fpost], (unsigned)(t + 1),
                                   __ATOMIC_RELAXED, __HIP_MEMORY_SCOPE_AGENT);
        } else {
            const int idx = batch * HID + col;
            out[65536 + idx]  = hv;
            out[131072 + idx] = cv;
        }
    }
}

// ====================== FALLBACK (round-5, verbatim) =======================
__device__ __forceinline__ void mfma_x(const __bf16* __restrict__ act,
                                       const bf16x8 (&wfr)[2][8],
                                       f32x4 (&acc)[2][4]) {
    #pragma unroll
    for (int kk = 0; kk < 8; ++kk) {
        bf16x8 bfr[4];
        #pragma unroll
        for (int nt = 0; nt < 4; ++nt)
            bfr[nt] = *(const bf16x8*)(act + kk * 2048 + nt * 128);
        #pragma unroll
        for (int mt = 0; mt < 2; ++mt)
            #pragma unroll
            for (int nt = 0; nt < 4; ++nt)
                acc[mt][nt] = __builtin_amdgcn_mfma_f32_16x16x32_bf16(
                    wfr[mt][kk], bfr[nt], acc[mt][nt], 0, 0, 0);
    }
}

template <bool RING>
__global__ __launch_bounds__(256, 1) void lstm_kernel(
    const float* __restrict__ c0,
    const float* __restrict__ W_ih, const float* __restrict__ W_hh,
    const float* __restrict__ b_ih, const float* __restrict__ b_hh,
    const __bf16* __restrict__ xbf,
    __bf16* hbuf,
    unsigned* bar,
    float* __restrict__ out)
{
    const int tid  = threadIdx.x;
    const int lane = tid & 63;
    const int w    = tid >> 6;
    const int quad = lane >> 4;
    const int l15  = lane & 15;
    const int hbase = blockIdx.x * 8;

    __shared__ float red[4][64][44];

    bf16x8 wfx[2][8], wfh[2][8];
    #pragma unroll
    for (int mt = 0; mt < 2; ++mt) {
        const int n    = mt * 16 + l15;
        const int grow = (n >> 3) * HID + hbase + (n & 7);
        #pragma unroll
        for (int kk = 0; kk < 8; ++kk) {
            const int kcol = w * 256 + kk * 32 + quad * 8;
            {
                const float* src = W_ih + (size_t)grow * 1024 + kcol;
                f32x4 a = *(const f32x4*)src;
                f32x4 b = *(const f32x4*)(src + 4);
                bf16x8 f;
                f[0]=(__bf16)a[0]; f[1]=(__bf16)a[1]; f[2]=(__bf16)a[2]; f[3]=(__bf16)a[3];
                f[4]=(__bf16)b[0]; f[5]=(__bf16)b[1]; f[6]=(__bf16)b[2]; f[7]=(__bf16)b[3];
                wfx[mt][kk] = f;
            }
            {
                const float* src = W_hh + (size_t)grow * 1024 + kcol;
                f32x4 a = *(const f32x4*)src;
                f32x4 b = *(const f32x4*)(src + 4);
                bf16x8 f;
                f[0]=(__bf16)a[0]; f[1]=(__bf16)a[1]; f[2]=(__bf16)a[2]; f[3]=(__bf16)a[3];
                f[4]=(__bf16)b[0]; f[5]=(__bf16)b[1]; f[6]=(__bf16)b[2]; f[7]=(__bf16)b[3];
                wfh[mt][kk] = f;
            }
        }
    }

    const int p0 = tid * 2;
    const int cb = p0 >> 3;
    const int cu = p0 & 7;
    float c0v = c0[cb * HID + hbase + cu];
    float c1v = c0[cb * HID + hbase + cu + 1];

    float bias0[4], bias1[4];
    #pragma unroll
    for (int gate = 0; gate < 4; ++gate) {
        int gr = gate * HID + hbase + cu;
        bias0[gate] = b_ih[gr] + b_hh[gr];
        bias1[gate] = b_ih[gr + 1] + b_hh[gr + 1];
    }

    const int lane_off = (32 * w + quad) * 512 + l15 * 8;
    const int hstore_off = blockIdx.x * 512 + cb * 8 + cu;

    f32x4 acc[2][4];
    #pragma unroll
    for (int mt = 0; mt < 2; ++mt)
        #pragma unroll
        for (int nt = 0; nt < 4; ++nt) { f32x4 z = {0.f,0.f,0.f,0.f}; acc[mt][nt] = z; }
    mfma_x(xbf + lane_off, wfx, acc);

    const int pf0 = 128 * w + lane;
    const int pf1 = 128 * w + 64 + lane;

    for (int t = 0; t < L_STEPS; ++t) {
        for (;;) {
            unsigned f0 = __hip_atomic_load(&bar[pf0], __ATOMIC_RELAXED,
                                            __HIP_MEMORY_SCOPE_AGENT);
            unsigned f1 = __hip_atomic_load(&bar[pf1], __ATOMIC_RELAXED,
                                            __HIP_MEMORY_SCOPE_AGENT);
            if (__all((f0 >= (unsigned)t) && (f1 >= (unsigned)t))) break;
            __builtin_amdgcn_s_sleep(1);
        }

        u32x4 hb[8][4];
        const __bf16* hb_base = hbuf
            + (size_t)(RING ? t : (t & 1)) * (NB * HID) + lane_off;
        #pragma unroll
        for (int kk = 0; kk < 8; ++kk)
            #pragma unroll
            for (int nt = 0; nt < 4; ++nt) {
                const __bf16* p = hb_base + kk * 2048 + nt * 128;
                if constexpr (RING)
                    asm volatile("global_load_dwordx4 %0, %1, off"
                                 : "=v"(hb[kk][nt]) : "v"(p));
                else
                    asm volatile("global_load_dwordx4 %0, %1, off sc1"
                                 : "=v"(hb[kk][nt]) : "v"(p));
            }
        asm volatile("s_waitcnt vmcnt(16)"
            : "+v"(hb[0][0]), "+v"(hb[0][1]), "+v"(hb[0][2]), "+v"(hb[0][3]),
              "+v"(hb[1][0]), "+v"(hb[1][1]), "+v"(hb[1][2]), "+v"(hb[1][3]),
              "+v"(hb[2][0]), "+v"(hb[2][1]), "+v"(hb[2][2]), "+v"(hb[2][3]),
              "+v"(hb[3][0]), "+v"(hb[3][1]), "+v"(hb[3][2]), "+v"(hb[3][3]));
        #pragma unroll
        for (int kk = 0; kk < 4; ++kk)
            #pragma unroll
            for (int mt = 0; mt < 2; ++mt)
                #pragma unroll
                for (int nt = 0; nt < 4; ++nt)
                    acc[mt][nt] = __builtin_amdgcn_mfma_f32_16x16x32_bf16(
                        wfh[mt][kk], __builtin_bit_cast(bf16x8, hb[kk][nt]),
                        acc[mt][nt], 0, 0, 0);
        asm volatile("s_waitcnt vmcnt(0)"
            : "+v"(hb[4][0]), "+v"(hb[4][1]), "+v"(hb[4][2]), "+v"(hb[4][3]),
              "+v"(hb[5][0]), "+v"(hb[5][1]), "+v"(hb[5][2]), "+v"(hb[5][3]),
              "+v"(hb[6][0]), "+v"(hb[6][1]), "+v"(hb[6][2]), "+v"(hb[6][3]),
              "+v"(hb[7][0]), "+v"(hb[7][1]), "+v"(hb[7][2]), "+v"(hb[7][3]));
        #pragma unroll
        for (int kk = 4; kk < 8; ++kk)
            #pragma unroll
            for (int mt = 0; mt < 2; ++mt)
                #pragma unroll
                for (int nt = 0; nt < 4; ++nt)
                    acc[mt][nt] = __builtin_amdgcn_mfma_f32_16x16x32_bf16(
                        wfh[mt][kk], __builtin_bit_cast(bf16x8, hb[kk][nt]),
                        acc[mt][nt], 0, 0, 0);

        __syncthreads();

        #pragma unroll
        for (int mt = 0; mt < 2; ++mt)
            #pragma unroll
            for (int nt = 0; nt < 4; ++nt) {
                const int row0 = mt * 16 + quad * 4;
                const int col  = nt * 16 + l15;
                *(f32x4*)&red[w][col][row0] = acc[mt][nt];
            }
        __syncthreads();

        float h0v, h1v;
        {
            float z0[4], z1[4];
            #pragma unroll
            for (int gate = 0; gate < 4; ++gate) {
                const int row = gate * 8 + cu;
                f32x2 s0 = *(const f32x2*)&red[0][cb][row];
                f32x2 s1 = *(const f32x2*)&red[1][cb][row];
                f32x2 s2 = *(const f32x2*)&red[2][cb][row];
                f32x2 s3 = *(const f32x2*)&red[3][cb][row];
                z0[gate] = s0[0] + s1[0] + s2[0] + s3[0] + bias0[gate];
                z1[gate] = s0[1] + s1[1] + s2[1] + s3[1] + bias1[gate];
            }
            float ig = sigmoid_f(z0[0]), fg = sigmoid_f(z0[1]);
            float gg = tanh_f(z0[2]),    og = sigmoid_f(z0[3]);
            c0v = fg * c0v + ig * gg;
            h0v = og * tanh_f(c0v);
            ig = sigmoid_f(z1[0]); fg = sigmoid_f(z1[1]);
            gg = tanh_f(z1[2]);    og = sigmoid_f(z1[3]);
            c1v = fg * c1v + ig * gg;
            h1v = og * tanh_f(c1v);
        }

        {
            bf16x2 hv; hv[0] = (__bf16)h0v; hv[1] = (__bf16)h1v;
            unsigned hbits = __builtin_bit_cast(unsigned, hv);
            const __bf16* dst = hbuf
                + (size_t)(RING ? (t + 1) : ((t + 1) & 1)) * (NB * HID) + hstore_off;
            asm volatile("global_store_dword %0, %1, off sc1"
                         :: "v"(dst), "v"(hbits) : "memory");
        }
        if (t == L_STEPS - 1) {
            const int idx = cb * HID + hbase + cu;
            out[65536 + idx]      = h0v;
            out[65536 + idx + 1]  = h1v;
            out[131072 + idx]     = c0v;
            out[131072 + idx + 1] = c1v;
        }
        asm volatile("s_waitcnt vmcnt(0)" ::: "memory");
        if (lane == 0)
            __hip_atomic_store(&bar[blockIdx.x * 4 + w], (unsigned)(t + 1),
                               __ATOMIC_RELAXED, __HIP_MEMORY_SCOPE_AGENT);

        #pragma unroll
        for (int mt = 0; mt < 2; ++mt)
            #pragma unroll
            for (int nt = 0; nt < 4; ++nt) { f32x4 z = {0.f,0.f,0.f,0.f}; acc[mt][nt] = z; }
        if (t < L_STEPS - 1)
            mfma_x(xbf + (size_t)(t + 1) * (NB * HID) + lane_off, wfx, acc);
    }
}

__global__ void out_kernel(const float* __restrict__ base, const float* __restrict__ Wout,
                           const float* __restrict__ bout, float* __restrict__ y)
{
    const int wv   = (int)((blockIdx.x * 256u + threadIdx.x) >> 6);
    const int lane = threadIdx.x & 63;
    const int b = wv >> 10;
    const int i = wv & 1023;
    const f32x4* hp = (const f32x4*)(base + 65536 + b * HID);
    const f32x4* wp = (const f32x4*)(Wout + (size_t)i * HID);
    float acc = 0.f;
    #pragma unroll
    for (int q = 0; q < 4; ++q) {
        f32x4 hv = hp[q * 64 + lane];
        f32x4 wvv = wp[q * 64 + lane];
        acc += hv[0]*wvv[0] + hv[1]*wvv[1] + hv[2]*wvv[2] + hv[3]*wvv[3];
    }
    #pragma unroll
    for (int off = 32; off > 0; off >>= 1) acc += __shfl_down(acc, off);
    if (lane == 0) y[b * HID + i] = acc + bout[i];
}

extern "C" void kernel_launch(void* const* d_in, const int* in_sizes, int n_in,
                              void* d_out, int out_size, void* d_ws, size_t ws_size,
                              hipStream_t stream)
{
    const float* x    = (const float*)d_in[0];
    const float* h0   = (const float*)d_in[1];
    const float* c0   = (const float*)d_in[2];
    const float* W_ih = (const float*)d_in[3];
    const float* W_hh = (const float*)d_in[4];
    const float* b_ih = (const float*)d_in[5];
    const float* b_hh = (const float*)d_in[6];
    const float* Wout = (const float*)d_in[7];
    const float* bout = (const float*)d_in[8];
    float* out = (float*)d_out;
    char* ws = (char*)d_ws;

    const size_t XBF_B = 67108864ull;          // 512 x 131072 (also ring slots 1..511)
    const size_t H0_B  = 131072ull;            // ring slot 0
    const size_t ZX_B  = 536870912ull;         // 512 x 1MB fp32 gate partials
    const size_t BAR_B = 4096ull;
    const size_t need_new = XBF_B + H0_B + ZX_B + BAR_B;   // ~576 MB

    if (ws_size >= need_new) {
        __bf16*   xbf = (__bf16*)ws;
        __bf16*   h0s = (__bf16*)(ws + XBF_B);
        float*    zxb = (float*)(ws + XBF_B + H0_B);
        unsigned* bar = (unsigned*)(ws + XBF_B + H0_B + ZX_B);
        convert_kernel<<<16384, 256, 0, stream>>>(x, h0, xbf, h0s, bar);
        zx_kernel<<<256, 256, 0, stream>>>(xbf, W_ih, b_ih, b_hh, zxb);
        lstm_wave<<<128, 512, 0, stream>>>(c0, W_hh, xbf, h0s, zxb, bar, out);
        out_kernel<<<16384, 256, 0, stream>>>(out, Wout, bout, out);
        return;
    }

    // fallback: round-5 proven path
    const size_t RING_B = 513ull * 131072;
    const size_t need_ring = XBF_B + RING_B + 4096;
    const bool ring = ws_size >= need_ring;

    __bf16* xbf   = (__bf16*)(ws);
    __bf16* hbuf  = (__bf16*)(ws + XBF_B);
    unsigned* bar = (unsigned*)(ws + XBF_B + (ring ? RING_B : 262144));

    convert_kernel<<<16384, 256, 0, stream>>>(x, h0, xbf, hbuf, bar);
    if (ring)
        lstm_kernel<true><<<128, 256, 0, stream>>>(c0, W_ih, W_hh, b_ih, b_hh,
                                                   xbf, hbuf, bar, out);
    else
        lstm_kernel<false><<<128, 256, 0, stream>>>(c0, W_ih, W_hh, b_ih, b_hh,
                                                    xbf, hbuf, bar, out);
    out_kernel<<<16384, 256, 0, stream>>>(out, Wout, bout, out);
}